// Round 6
// baseline (30.973 us; speedup 1.0000x reference)
//
#include <hip/hip_runtime.h>

// Problem constants (match reference)
#define BB 128
#define CC 5
#define HH 128
#define WW 128
#define HWSZ (HH * WW)              // 16384
#define NCELLS (BB * HH * WW)       // 2,097,152
#define N4 (NCELLS / 4)             // 524,288 float4 cell-groups
#define GPT 2                        // float4-groups per thread
#define NTHREADS 256
#define NBLOCKS (N4 / (NTHREADS * GPT))   // 1024 blocks, exact
#define HALF (N4 / 2)                // 262,144

__device__ __forceinline__ float4 ld4(const float* p) {
    return *reinterpret_cast<const float4*>(p);
}

// Masked SSE for one float4 cell-group at flat group index gi.
__device__ __forceinline__ float group_sse(
    const float* __restrict__ labela,
    const float* __restrict__ labelb,
    const float* __restrict__ pred_ab,
    const float* __restrict__ pred_ba,
    int gi)
{
    const int cb = gi * 4;                    // base cell index (b*HW + hw)
    const int b  = cb >> 14;                  // / 16384
    const int hw = cb & (HWSZ - 1);
    const size_t base = (size_t)b * (CC * HWSZ) + hw;   // channel-0 offset

    const float4 m4 = ld4(labela + base);     // objectness mask quad

    float cell = 0.f;
    if (m4.x != 0.f || m4.y != 0.f || m4.z != 0.f || m4.w != 0.f) {
        float4 la[CC], pa[CC], lb[CC], pb[CC];
        la[0] = m4;
        #pragma unroll
        for (int c = 1; c < CC; ++c) la[c] = ld4(labela  + base + (size_t)c * HWSZ);
        #pragma unroll
        for (int c = 0; c < CC; ++c) pa[c] = ld4(pred_ab + base + (size_t)c * HWSZ);
        #pragma unroll
        for (int c = 0; c < CC; ++c) lb[c] = ld4(labelb  + base + (size_t)c * HWSZ);
        #pragma unroll
        for (int c = 0; c < CC; ++c) pb[c] = ld4(pred_ba + base + (size_t)c * HWSZ);

        float sx = 0.f, sy = 0.f, sz = 0.f, sw = 0.f;
        #pragma unroll
        for (int c = 0; c < CC; ++c) {
            float d;
            d = la[c].x - pa[c].x; sx += d * d;  d = lb[c].x - pb[c].x; sx += d * d;
            d = la[c].y - pa[c].y; sy += d * d;  d = lb[c].y - pb[c].y; sy += d * d;
            d = la[c].z - pa[c].z; sz += d * d;  d = lb[c].z - pb[c].z; sz += d * d;
            d = la[c].w - pa[c].w; sw += d * d;  d = lb[c].w - pb[c].w; sw += d * d;
        }
        cell = (m4.x != 0.f ? sx : 0.f)
             + (m4.y != 0.f ? sy : 0.f)
             + (m4.z != 0.f ? sz : 0.f)
             + (m4.w != 0.f ? sw : 0.f);
    }
    return cell;
}

// Kernel 1: each thread handles 2 independent float4-groups (opposite halves
// of the grid -> two independent load streams). Per-block partial -> ws[bid].
__global__ __launch_bounds__(NTHREADS) void yolo_partial_kernel(
    const float* __restrict__ labela,
    const float* __restrict__ labelb,
    const float* __restrict__ pred_ab,
    const float* __restrict__ pred_ba,
    float* __restrict__ ws)
{
    const int i0 = blockIdx.x * NTHREADS + threadIdx.x;
    float cell = group_sse(labela, labelb, pred_ab, pred_ba, i0)
               + group_sse(labela, labelb, pred_ab, pred_ba, i0 + HALF);

    // wave(64) shuffle reduction
    #pragma unroll
    for (int off = 32; off > 0; off >>= 1)
        cell += __shfl_down(cell, off, 64);

    __shared__ float wsum[NTHREADS / 64];
    const int lane = threadIdx.x & 63;
    const int wid  = threadIdx.x >> 6;
    if (lane == 0) wsum[wid] = cell;
    __syncthreads();
    if (threadIdx.x == 0) {
        float t = 0.f;
        #pragma unroll
        for (int w = 0; w < NTHREADS / 64; ++w) t += wsum[w];
        ws[blockIdx.x] = t;
    }
}

// Kernel 2: one wave reduces the 1024 partials -> out[0] (plain store; fully
// overwrites the harness's poison every call, so no memset is needed).
__global__ __launch_bounds__(64) void yolo_final_kernel(
    const float* __restrict__ ws,
    float* __restrict__ out)
{
    float s = 0.f;
    #pragma unroll
    for (int k = 0; k < NBLOCKS / 64; ++k)             // 16 strided loads/lane
        s += ws[threadIdx.x + k * 64];

    #pragma unroll
    for (int off = 32; off > 0; off >>= 1)
        s += __shfl_down(s, off, 64);

    if (threadIdx.x == 0) out[0] = s;
}

extern "C" void kernel_launch(void* const* d_in, const int* in_sizes, int n_in,
                              void* d_out, int out_size, void* d_ws, size_t ws_size,
                              hipStream_t stream) {
    const float* labela  = (const float*)d_in[0];
    const float* labelb  = (const float*)d_in[1];
    const float* pred_ab = (const float*)d_in[2];
    const float* pred_ba = (const float*)d_in[3];
    float* ws  = (float*)d_ws;    // 1024 floats = 4 KB of scratch
    float* out = (float*)d_out;

    yolo_partial_kernel<<<NBLOCKS, NTHREADS, 0, stream>>>(labela, labelb, pred_ab, pred_ba, ws);
    yolo_final_kernel<<<1, 64, 0, stream>>>(ws, out);
}